// Round 6
// baseline (514.065 us; speedup 1.0000x reference)
//
#include <hip/hip_runtime.h>

// Problem constants: S=1024, B=8, E=1024, H=16, HD=64
#define M_TOK 8192   // S*B
#define SEQ   1024
#define NB    8
#define EMB   1024
#define NH    16

typedef float  f32x4 __attribute__((ext_vector_type(4)));
typedef __bf16 bf16x8 __attribute__((ext_vector_type(8)));
typedef unsigned short u16x8 __attribute__((ext_vector_type(8)));
typedef unsigned short u16x4 __attribute__((ext_vector_type(4)));

__device__ __forceinline__ unsigned short f2bf(float f) {
  unsigned int u = __builtin_bit_cast(unsigned int, f);
  return (unsigned short)((u + 0x7fffu + ((u >> 16) & 1u)) >> 16);
}

__device__ __forceinline__ f32x4 mfma_bf16(u16x8 a, u16x8 b, f32x4 c) {
  return __builtin_amdgcn_mfma_f32_16x16x32_bf16(
      __builtin_bit_cast(bf16x8, a), __builtin_bit_cast(bf16x8, b), c, 0, 0, 0);
}

__device__ __forceinline__ void gload_lds16(const void* g, void* l) {
  __builtin_amdgcn_global_load_lds(
      (const __attribute__((address_space(1))) void*)g,
      (__attribute__((address_space(3))) void*)l, 16, 0, 0);
}

// ---------------------------------------------------------------- converts
__global__ __launch_bounds__(256) void cvt_kernel(const float* __restrict__ src,
                                                  unsigned short* __restrict__ dst,
                                                  int n) {
  int i = (blockIdx.x * 256 + threadIdx.x) * 4;
  if (i >= n) return;
  float4 v = *reinterpret_cast<const float4*>(src + i);
  u16x4 o = {f2bf(v.x), f2bf(v.y), f2bf(v.z), f2bf(v.w)};
  *reinterpret_cast<u16x4*>(dst + i) = o;
}

__global__ __launch_bounds__(256) void cvtneg_kernel(const float* __restrict__ src,
                                                     unsigned short* __restrict__ dst,
                                                     int n) {
  int i = (blockIdx.x * 256 + threadIdx.x) * 4;
  if (i >= n) return;
  float4 v = *reinterpret_cast<const float4*>(src + i);
  u16x4 o = {f2bf(-v.x), f2bf(-v.y), f2bf(-v.z), f2bf(-v.w)};
  *reinterpret_cast<u16x4*>(dst + i) = o;
}

// activation convert with batch-major row permutation: dst row m' = b*1024+s
// grid (8192, 6), block 256
__global__ __launch_bounds__(256) void cvt6p_kernel(
    const float* __restrict__ s0, const float* __restrict__ s1,
    const float* __restrict__ s2, const float* __restrict__ s3,
    const float* __restrict__ s4, const float* __restrict__ s5,
    unsigned short* __restrict__ d0, unsigned short* __restrict__ d1,
    unsigned short* __restrict__ d2, unsigned short* __restrict__ d3,
    unsigned short* __restrict__ d4, unsigned short* __restrict__ d5) {
  int which = blockIdx.y;
  const float* src = (which == 0) ? s0 : (which == 1) ? s1 : (which == 2) ? s2
                     : (which == 3) ? s3 : (which == 4) ? s4 : s5;
  unsigned short* dst = (which == 0) ? d0 : (which == 1) ? d1 : (which == 2) ? d2
                        : (which == 3) ? d3 : (which == 4) ? d4 : d5;
  int mp = blockIdx.x;             // m' = b*1024 + s
  int b = mp >> 10, s = mp & 1023;
  const float* srow = src + (size_t)(s * 8 + b) * 1024;
  int tid = threadIdx.x;
  float4 v = *reinterpret_cast<const float4*>(srow + tid * 4);
  u16x4 o = {f2bf(v.x), f2bf(v.y), f2bf(v.z), f2bf(v.w)};
  *reinterpret_cast<u16x4*>(dst + (size_t)mp * 1024 + tid * 4) = o;
}

// ---------------------------------------------------------------- QKV proj
// K-folded real GEMM: M=8192 (m'=b*1024+s), N=6144 (n'=sec*2048+h*128+im*64+d),
// K=2048 ([re|im]). B-rows pick {wr, wi, -wi} per (im, part).
// 256x256 tile, BK=32, 8 waves (2x4), 3 LDS bufs, 2-phase interleaved schedule:
// per phase {ds_read subtile, half-STAGE issue, bar, lgkm0, setprio, 16 MFMA, bar}.
__global__ __launch_bounds__(512, 2) void proj8(
    const unsigned short* __restrict__ qreb, const unsigned short* __restrict__ qimb,
    const unsigned short* __restrict__ kreb, const unsigned short* __restrict__ kimb,
    const unsigned short* __restrict__ vreb, const unsigned short* __restrict__ vimb,
    const unsigned short* __restrict__ wr, const unsigned short* __restrict__ wi,
    const unsigned short* __restrict__ win, const float* __restrict__ br,
    const float* __restrict__ bi, unsigned short* __restrict__ q2,
    unsigned short* __restrict__ k2, unsigned short* __restrict__ vt) {
  // 3 bufs x (A 16KB + B 16KB) = 96 KB; epilogue reuses the pool
  __shared__ __align__(16) unsigned short smem[49152];

  const int tid = threadIdx.x;
  const int lane = tid & 63, w = tid >> 6;
  const int lr = lane & 15, lk = lane >> 4;
  const int wrw = w >> 2, wc = w & 3;   // wave grid 2(M) x 4(N)

  // XCD bijective swizzle: 768 blocks = 8 XCD x 96
  const int lin = blockIdx.x;
  const int wg = (lin & 7) * 96 + (lin >> 3);
  const int mt = wg / 24, nb = wg % 24;   // n-fastest: A-panel reuse in L2
  const int m0 = mt * 256;                // m' space
  const int n0 = nb * 256;                // n' space
  const int sec = n0 >> 11;
  const int bb = m0 >> 10;                // batch
  const int s0 = m0 & 1023;

  const unsigned short* aRe = (sec == 0) ? qreb : (sec == 1) ? kreb : vreb;
  const unsigned short* aIm = (sec == 0) ? qimb : (sec == 1) ? kimb : vimb;

  // staging precompute: granule gd = i*512 + tid; row = gd>>2; g = gd&3;
  // swizzled source granule gsw = g ^ ((row>>1)&3)  (64B rows, 4 granules)
  const int gsw = (tid & 3) ^ ((tid >> 3) & 3);     // same for i=0,1
  const int arow0 = (tid >> 2);                     // 0..127
  const unsigned int aoff0 = (unsigned int)(m0 + arow0) * 1024u + gsw * 8;
  const unsigned int aoff1 = (unsigned int)(m0 + 128 + arow0) * 1024u + gsw * 8;
  // B rows: n' = n0 + rl ; pick tensor by (im, part)
  const unsigned short* pB0[2];   // part0 (k'<1024)
  const unsigned short* pB1[2];   // part1
#pragma unroll
  for (int i = 0; i < 2; ++i) {
    int rl = i * 128 + arow0;
    int np = n0 + rl;
    int nn = np & 2047;
    int im_ = (nn >> 6) & 1;
    int orig = sec * 1024 + ((nn >> 7) << 6) + (nn & 63);
    const unsigned short* t0 = im_ ? wi : wr;
    const unsigned short* t1 = im_ ? wr : win;
    pB0[i] = t0 + (size_t)orig * 1024 + gsw * 8;
    pB1[i] = t1 + (size_t)orig * 1024 + gsw * 8;
  }

#define STAGE_A(ts, cb)                                                        \
  do {                                                                         \
    const int kk_ = ((ts) & 31) * 32;                                          \
    const unsigned short* as_ = ((ts) < 32) ? aRe : aIm;                       \
    gload_lds16(as_ + aoff0 + kk_, &smem[(cb) * 16384 + w * 512]);             \
    gload_lds16(as_ + aoff1 + kk_, &smem[(cb) * 16384 + 4096 + w * 512]);      \
  } while (0)
#define STAGE_B(ts, cb)                                                        \
  do {                                                                         \
    const int kk_ = ((ts) & 31) * 32;                                          \
    const unsigned short* b0_ = ((ts) < 32) ? pB0[0] : pB1[0];                 \
    const unsigned short* b1_ = ((ts) < 32) ? pB0[1] : pB1[1];                 \
    gload_lds16(b0_ + kk_, &smem[(cb) * 16384 + 8192 + w * 512]);              \
    gload_lds16(b1_ + kk_, &smem[(cb) * 16384 + 12288 + w * 512]);             \
  } while (0)

  f32x4 acc[8][4];
#pragma unroll
  for (int i = 0; i < 8; ++i)
#pragma unroll
    for (int j = 0; j < 4; ++j) acc[i][j] = {0.f, 0.f, 0.f, 0.f};

  STAGE_A(0, 0);
  STAGE_B(0, 0);
  STAGE_A(1, 1);
  STAGE_B(1, 1);
  asm volatile("s_waitcnt vmcnt(4)" ::: "memory");
  __builtin_amdgcn_s_barrier();

  const int g8 = (lk ^ ((lr >> 1) & 3)) * 8;   // fragment read swizzle
  int c = 0;
#pragma unroll 1
  for (int t = 0; t < 64; ++t) {
    const unsigned short* base = &smem[c * 16384];
    const int cp2 = (c == 0) ? 2 : c - 1;      // buffer for tile t+2
    u16x8 aF[8], bF[4];

    // ---------------- phase 1: cluster1 reads + A-half stage ----------------
#pragma unroll
    for (int mi = 0; mi < 4; ++mi)
      aF[mi] = *(const u16x8*)(base + (wrw * 128 + mi * 16 + lr) * 32 + g8);
#pragma unroll
    for (int ni = 0; ni < 4; ++ni)
      bF[ni] = *(const u16x8*)(base + 8192 + (wc * 64 + ni * 16 + lr) * 32 + g8);
    if (t < 62) STAGE_A(t + 2, cp2);
    __builtin_amdgcn_s_barrier();
    asm volatile("s_waitcnt lgkmcnt(0)" ::: "memory");
    __builtin_amdgcn_sched_barrier(0);
    __builtin_amdgcn_s_setprio(1);
#pragma unroll
    for (int mi = 0; mi < 4; ++mi)
#pragma unroll
      for (int ni = 0; ni < 4; ++ni)
        acc[mi][ni] = mfma_bf16(aF[mi], bF[ni], acc[mi][ni]);
    __builtin_amdgcn_s_setprio(0);
    __builtin_amdgcn_s_barrier();

    // ---------------- phase 2: cluster2 reads + B-half stage + vmcnt --------
#pragma unroll
    for (int mi = 4; mi < 8; ++mi)
      aF[mi] = *(const u16x8*)(base + (wrw * 128 + mi * 16 + lr) * 32 + g8);
    if (t < 62) {
      STAGE_B(t + 2, cp2);
      asm volatile("s_waitcnt vmcnt(4)" ::: "memory");
    } else if (t == 62) {
      asm volatile("s_waitcnt vmcnt(0)" ::: "memory");
    }
    __builtin_amdgcn_s_barrier();
    asm volatile("s_waitcnt lgkmcnt(0)" ::: "memory");
    __builtin_amdgcn_sched_barrier(0);
    __builtin_amdgcn_s_setprio(1);
#pragma unroll
    for (int mi = 4; mi < 8; ++mi)
#pragma unroll
      for (int ni = 0; ni < 4; ++ni)
        acc[mi][ni] = mfma_bf16(aF[mi], bF[ni], acc[mi][ni]);
    __builtin_amdgcn_s_setprio(0);
    __builtin_amdgcn_s_barrier();

    c = (c == 2) ? 0 : c + 1;
  }
#undef STAGE_A
#undef STAGE_B

  // ---- epilogue ----
  float vb[4];
#pragma unroll
  for (int ni = 0; ni < 4; ++ni) {
    int np = n0 + wc * 64 + ni * 16 + lr;
    int nn = np & 2047;
    int im_ = (nn >> 6) & 1;
    int orig = sec * 1024 + ((nn >> 7) << 6) + (nn & 63);
    vb[ni] = im_ ? bi[orig] : br[orig];
  }
  const int h0 = (n0 & 2047) >> 7;
  const int bh_base = bb * 16 + h0;

  if (sec < 2) {
    unsigned short* dst = (sec == 0) ? q2 : k2;
    unsigned short (*sE)[264] = (unsigned short (*)[264])smem;  // [128][264]
    for (int p = 0; p < 2; ++p) {
      __syncthreads();
      if (wrw == p) {
#pragma unroll
        for (int mi = 0; mi < 8; ++mi)
#pragma unroll
          for (int ni = 0; ni < 4; ++ni)
#pragma unroll
            for (int r = 0; r < 4; ++r)
              sE[mi * 16 + lk * 4 + r][wc * 64 + ni * 16 + lr] =
                  f2bf(acc[mi][ni][r] + vb[ni]);
      }
      __syncthreads();
#pragma unroll
      for (int it = 0; it < 8; ++it) {
        int cc = it * 512 + tid;
        int row = cc >> 5, nl = (cc & 31) * 8;
        int h_i = nl >> 7, off = nl & 127;
        u16x8 v = *(const u16x8*)&sE[row][nl];
        *(u16x8*)(dst + (size_t)(bh_base + h_i) * 131072 +
                  (size_t)(s0 + p * 128 + row) * 128 + off) = v;
      }
    }
  } else {
    unsigned short (*sEt)[136] = (unsigned short (*)[136])smem;  // [256][136]
    for (int p = 0; p < 2; ++p) {
      __syncthreads();
      if (wrw == p) {
#pragma unroll
        for (int mi = 0; mi < 8; ++mi)
#pragma unroll
          for (int ni = 0; ni < 4; ++ni) {
            u16x4 pk = {f2bf(acc[mi][ni][0] + vb[ni]), f2bf(acc[mi][ni][1] + vb[ni]),
                        f2bf(acc[mi][ni][2] + vb[ni]), f2bf(acc[mi][ni][3] + vb[ni])};
            *(u16x4*)&sEt[wc * 64 + ni * 16 + lr][mi * 16 + lk * 4] = pk;
          }
      }
      __syncthreads();
#pragma unroll
      for (int it = 0; it < 8; ++it) {
        int cc = it * 512 + tid;
        int nrow = cc >> 4, m8 = (cc & 15) * 8;
        int h_i = nrow >> 7, dd = nrow & 127;
        u16x8 v = *(const u16x8*)&sEt[nrow][m8];
        *(u16x8*)(vt + (size_t)(bh_base + h_i) * 131072 + (size_t)dd * 1024 +
                  s0 + p * 128 + m8) = v;
      }
    }
  }
}

// ---------------------------------------------------------------- attention
// 1D grid 2048 with XCD-locality mapping: each XCD runs one bh's 16 q-tiles
// consecutively so K/V stay L2-resident. 256 thr = 4 waves x 16 q-rows.
// LDS tiles XOR-swizzled (16B granule ^= row&7) via pre-swizzled global source
__global__ __launch_bounds__(256, 2) void attn_kernel(
    const unsigned short* __restrict__ q2, const unsigned short* __restrict__ k2,
    const unsigned short* __restrict__ vt,
    unsigned short* __restrict__ aor, unsigned short* __restrict__ aoi) {
  __shared__ unsigned short sQ[64][128];
  __shared__ unsigned short sK[64][128];
  __shared__ unsigned short sV[128][64];
  __shared__ unsigned short sP[4][16][72];  // +8 pad -> ~2-way

  const int tid = threadIdx.x, lane = tid & 63, w = tid >> 6;
  const int lr = lane & 15, lk = lane >> 4;
  const int lin = blockIdx.x;
  const int idx = lin >> 3;
  const int bh = (lin & 7) * 16 + (idx >> 4);
  const int q0 = (idx & 15) * 64;
  const int bb = bh >> 4, hh = bh & 15;

  // stage Q tile (64 x 128) once, swizzled source
  const unsigned short* qbase = q2 + (size_t)bh * 131072 + (size_t)q0 * 128;
  for (int c = 0; c < 4; ++c) {
    int rb = (w * 4 + c) * 4;
    int row = rb + (lane >> 4);
    int blk = (lane & 15) ^ (row & 7);
    gload_lds16(qbase + (size_t)row * 128 + blk * 8, &sQ[rb][0]);
  }

  f32x4 o[8];
  for (int i = 0; i < 8; ++i) o[i] = {0.f, 0.f, 0.f, 0.f};
  float mrun[4] = {-1e30f, -1e30f, -1e30f, -1e30f};
  float lrun[4] = {0.f, 0.f, 0.f, 0.f};
  const float SC = 0.125f;  // 1/sqrt(64)

  const int qrow = w * 16 + lr;
  const int qsw = qrow & 7;

  for (int t0 = 0; t0 < 1024; t0 += 64) {
    const unsigned short* kb = k2 + (size_t)bh * 131072 + (size_t)t0 * 128;
    for (int c = 0; c < 4; ++c) {
      int rb = (w * 4 + c) * 4;
      int row = rb + (lane >> 4);
      int blk = (lane & 15) ^ (row & 7);
      gload_lds16(kb + (size_t)row * 128 + blk * 8, &sK[rb][0]);
    }
    const unsigned short* vb = vt + (size_t)bh * 131072 + t0;
    for (int c = 0; c < 4; ++c) {
      int rb = (w * 4 + c) * 8;
      int row = rb + (lane >> 3);
      int blk = (lane & 7) ^ (row & 7);
      gload_lds16(vb + (size_t)row * 1024 + blk * 8, &sV[rb][0]);
    }
    __syncthreads();

    // scores tile: rows = wave's 16 q-rows, cols = 64 t
    f32x4 sc[4];
    for (int nj = 0; nj < 4; ++nj) sc[nj] = {0.f, 0.f, 0.f, 0.f};
    for (int ks = 0; ks < 4; ++ks) {
      u16x8 qf = *(const u16x8*)&sQ[qrow][((ks * 4 + lk) ^ qsw) * 8];
      for (int nj = 0; nj < 4; ++nj) {
        int krow = nj * 16 + lr;
        u16x8 kf = *(const u16x8*)&sK[krow][((ks * 4 + lk) ^ (krow & 7)) * 8];
        sc[nj] = mfma_bf16(qf, kf, sc[nj]);
      }
    }

    // online softmax (row r of this lane = 4*lk + r)
    for (int r = 0; r < 4; ++r) {
      float s0 = sc[0][r] * SC, s1 = sc[1][r] * SC;
      float s2 = sc[2][r] * SC, s3 = sc[3][r] * SC;
      float mx = fmaxf(fmaxf(s0, s1), fmaxf(s2, s3));
      for (int msk = 1; msk < 16; msk <<= 1) mx = fmaxf(mx, __shfl_xor(mx, msk));
      float mnew = fmaxf(mrun[r], mx);
      float corr = __expf(mrun[r] - mnew);
      float p0 = __expf(s0 - mnew), p1 = __expf(s1 - mnew);
      float p2 = __expf(s2 - mnew), p3 = __expf(s3 - mnew);
      float rs = p0 + p1 + p2 + p3;
      for (int msk = 1; msk < 16; msk <<= 1) rs += __shfl_xor(rs, msk);
      lrun[r] = lrun[r] * corr + rs;
      mrun[r] = mnew;
      for (int ni = 0; ni < 8; ++ni) o[ni][r] *= corr;
      int prow = lk * 4 + r;
      sP[w][prow][0 * 16 + lr] = f2bf(p0);
      sP[w][prow][1 * 16 + lr] = f2bf(p1);
      sP[w][prow][2 * 16 + lr] = f2bf(p2);
      sP[w][prow][3 * 16 + lr] = f2bf(p3);
    }

    // PV: O[s, dd] += P[s, t] * VT[dd, t]
    for (int ks = 0; ks < 2; ++ks) {
      u16x8 pf = *(const u16x8*)&sP[w][lr][ks * 32 + lk * 8];
      for (int ni = 0; ni < 8; ++ni) {
        int vrow = ni * 16 + lr;
        u16x8 vf = *(const u16x8*)&sV[vrow][((ks * 4 + lk) ^ (vrow & 7)) * 8];
        o[ni] = mfma_bf16(pf, vf, o[ni]);
      }
    }
    __syncthreads();
  }

  for (int r = 0; r < 4; ++r) {
    float inv = 1.0f / lrun[r];
    for (int ni = 0; ni < 8; ++ni) o[ni][r] *= inv;
  }
  for (int ni = 0; ni < 8; ++ni) {
    int dd = ni * 16 + lr;
    for (int r = 0; r < 4; ++r) {
      int sg = q0 + w * 16 + lk * 4 + r;
      size_t tok = (size_t)sg * 8 + bb;
      if (dd < 64)
        aor[tok * 1024 + hh * 64 + dd] = f2bf(o[ni][r]);
      else
        aoi[tok * 1024 + hh * 64 + (dd - 64)] = f2bf(o[ni][r]);
    }
  }
}

// ---------------------------------------------------------------- out proj
// Combined [128][re32|im32] XOR-swizzled tiles; XCD swizzle (512 = 8 x 64).
__global__ __launch_bounds__(256, 2) void out_gemm(
    const unsigned short* __restrict__ ar, const unsigned short* __restrict__ ai,
    const unsigned short* __restrict__ wr, const unsigned short* __restrict__ wi,
    const float* __restrict__ br, const float* __restrict__ bi,
    float* __restrict__ out) {
  __shared__ __align__(16) unsigned short smem[16384];  // 32 KB
  unsigned short (*sA)[64] = (unsigned short (*)[64])(smem);
  unsigned short (*sW)[64] = (unsigned short (*)[64])(smem + 8192);

  const int tid = threadIdx.x;
  const int lane = tid & 63;
  const int w = tid >> 6;
  const int lr = lane & 15, lk = lane >> 4;
  const int wm = (w & 1) * 64, wn = (w >> 1) * 64;

  const int lin = blockIdx.x;
  const int wg = (lin & 7) * 64 + (lin >> 3);
  const int n0 = (wg & 7) * 128;
  const int m0 = (wg >> 3) * 128;

  int srow[4], sgsw[4];
  for (int c = 0; c < 4; ++c) {
    int gid = c * 256 + tid;
    srow[c] = gid >> 3;
    sgsw[c] = (gid & 7) ^ (srow[c] & 7);
  }

  f32x4 accre[4][4], accim[4][4];
  for (int i = 0; i < 4; ++i)
    for (int j = 0; j < 4; ++j) {
      accre[i][j] = {0.f, 0.f, 0.f, 0.f};
      accim[i][j] = {0.f, 0.f, 0.f, 0.f};
    }
  const u16x8 sign8 = {0x8000, 0x8000, 0x8000, 0x8000, 0x8000, 0x8000, 0x8000, 0x8000};

  for (int k0 = 0; k0 < 1024; k0 += 32) {
    for (int c = 0; c < 4; ++c) {
      int row = srow[c], gsw = sgsw[c];
      int kcol = k0 + (gsw & 3) * 8;
      size_t aoff = (size_t)(m0 + row) * 1024 + kcol;
      gload_lds16((gsw < 4 ? ar : ai) + aoff, smem + (c * 256 + w * 64) * 8);
      size_t woff = (size_t)(n0 + row) * 1024 + kcol;
      gload_lds16((gsw < 4 ? wr : wi) + woff, smem + 8192 + (c * 256 + w * 64) * 8);
    }
    __syncthreads();

    u16x8 fWr[4], fWi[4];
    for (int ni = 0; ni < 4; ++ni) {
      int R = wn + ni * 16 + lr, sw = R & 7;
      fWr[ni] = *(const u16x8*)&sW[R][(lk ^ sw) * 8];
      fWi[ni] = *(const u16x8*)&sW[R][((4 + lk) ^ sw) * 8];
    }
    for (int mi = 0; mi < 4; ++mi) {
      int R = wm + mi * 16 + lr, sw = R & 7;
      u16x8 a_r = *(const u16x8*)&sA[R][(lk ^ sw) * 8];
      u16x8 a_i = *(const u16x8*)&sA[R][((4 + lk) ^ sw) * 8];
      u16x8 na_i = a_i ^ sign8;
      for (int ni = 0; ni < 4; ++ni) {
        accre[mi][ni] = mfma_bf16(a_r, fWr[ni], accre[mi][ni]);
        accre[mi][ni] = mfma_bf16(na_i, fWi[ni], accre[mi][ni]);
        accim[mi][ni] = mfma_bf16(a_r, fWi[ni], accim[mi][ni]);
        accim[mi][ni] = mfma_bf16(a_i, fWr[ni], accim[mi][ni]);
      }
    }
    __syncthreads();
  }

  for (int ni = 0; ni < 4; ++ni) {
    int n = n0 + wn + ni * 16 + lr;
    float vbr = br[n], vbi = bi[n];
    for (int mi = 0; mi < 4; ++mi) {
      for (int r = 0; r < 4; ++r) {
        int m = m0 + wm + mi * 16 + lk * 4 + r;
        out[(size_t)m * 1024 + n] = accre[mi][ni][r] + vbr;
        out[8388608 + (size_t)m * 1024 + n] = accim[mi][ni][r] + vbi;
      }
    }
  }
}

// ---------------------------------------------------------------- launch
extern "C" void kernel_launch(void* const* d_in, const int* in_sizes, int n_in,
                              void* d_out, int out_size, void* d_ws, size_t ws_size,
                              hipStream_t stream) {
  const float* qre = (const float*)d_in[0];
  const float* qim = (const float*)d_in[1];
  const float* kre = (const float*)d_in[2];
  const float* kim = (const float*)d_in[3];
  const float* vre = (const float*)d_in[4];
  const float* vim = (const float*)d_in[5];
  const float* wqkv_re = (const float*)d_in[6];
  const float* wqkv_im = (const float*)d_in[7];
  const float* bqr = (const float*)d_in[8];
  const float* bqi = (const float*)d_in[9];
  const float* wo_re = (const float*)d_in[10];
  const float* wo_im = (const float*)d_in[11];
  const float* bor = (const float*)d_in[12];
  const float* boi = (const float*)d_in[13];

  char* ws = (char*)d_ws;
  unsigned short* wr_bf = (unsigned short*)(ws + 0);           // 6.29 MB
  unsigned short* wi_bf = (unsigned short*)(ws + 6291456);
  unsigned short* win   = (unsigned short*)(ws + 12582912);    // -Wi
  unsigned short* wor_bf = (unsigned short*)(ws + 18874368);
  unsigned short* woi_bf = (unsigned short*)(ws + 20971520);
  // activations bf16, batch-major rows (dead after proj8)
  unsigned short* qreb = (unsigned short*)(ws + 23068672);
  unsigned short* qimb = (unsigned short*)(ws + 39845888);
  unsigned short* kreb = (unsigned short*)(ws + 56623104);
  unsigned short* kimb = (unsigned short*)(ws + 73400320);
  unsigned short* vreb = (unsigned short*)(ws + 90177536);
  unsigned short* vimb = (unsigned short*)(ws + 106954752);
  unsigned short* q2 = (unsigned short*)(ws + 123731968);      // 33.55 MB
  unsigned short* k2 = (unsigned short*)(ws + 157286400);
  unsigned short* vt = (unsigned short*)(ws + 190840832);      // ends 224.4 MB
  // attn outputs alias the dead activation region
  unsigned short* aor = (unsigned short*)(ws + 23068672);
  unsigned short* aoi = (unsigned short*)(ws + 39845888);

  cvt_kernel<<<3072, 256, 0, stream>>>(wqkv_re, wr_bf, 3145728);
  cvt_kernel<<<3072, 256, 0, stream>>>(wqkv_im, wi_bf, 3145728);
  cvtneg_kernel<<<3072, 256, 0, stream>>>(wqkv_im, win, 3145728);
  cvt_kernel<<<1024, 256, 0, stream>>>(wo_re, wor_bf, 1048576);
  cvt_kernel<<<1024, 256, 0, stream>>>(wo_im, woi_bf, 1048576);
  cvt6p_kernel<<<dim3(8192, 6), 256, 0, stream>>>(qre, qim, kre, kim, vre, vim,
                                                  qreb, qimb, kreb, kimb, vreb, vimb);

  proj8<<<768, 512, 0, stream>>>(qreb, qimb, kreb, kimb, vreb, vimb,
                                 wr_bf, wi_bf, win, bqr, bqi, q2, k2, vt);
  attn_kernel<<<2048, 256, 0, stream>>>(q2, k2, vt, aor, aoi);
  out_gemm<<<512, 256, 0, stream>>>(aor, aoi, wor_bf, woi_bf, bor, boi,
                                    (float*)d_out);
}

// Round 8
// 482.970 us; speedup vs baseline: 1.0644x; 1.0644x over previous
//
#include <hip/hip_runtime.h>

// Problem constants: S=1024, B=8, E=1024, H=16, HD=64
#define M_TOK 8192   // S*B
#define SEQ   1024
#define NB    8
#define EMB   1024
#define NH    16

typedef float  f32x4 __attribute__((ext_vector_type(4)));
typedef __bf16 bf16x8 __attribute__((ext_vector_type(8)));
typedef unsigned short u16x8 __attribute__((ext_vector_type(8)));
typedef unsigned short u16x4 __attribute__((ext_vector_type(4)));

__device__ __forceinline__ unsigned short f2bf(float f) {
  unsigned int u = __builtin_bit_cast(unsigned int, f);
  return (unsigned short)((u + 0x7fffu + ((u >> 16) & 1u)) >> 16);
}

__device__ __forceinline__ f32x4 mfma_bf16(u16x8 a, u16x8 b, f32x4 c) {
  return __builtin_amdgcn_mfma_f32_16x16x32_bf16(
      __builtin_bit_cast(bf16x8, a), __builtin_bit_cast(bf16x8, b), c, 0, 0, 0);
}

__device__ __forceinline__ void gload_lds16(const void* g, void* l) {
  __builtin_amdgcn_global_load_lds(
      (const __attribute__((address_space(1))) void*)g,
      (__attribute__((address_space(3))) void*)l, 16, 0, 0);
}

// ---------------------------------------------------------------- converts
__global__ __launch_bounds__(256) void cvt_kernel(const float* __restrict__ src,
                                                  unsigned short* __restrict__ dst,
                                                  int n) {
  int i = (blockIdx.x * 256 + threadIdx.x) * 4;
  if (i >= n) return;
  float4 v = *reinterpret_cast<const float4*>(src + i);
  u16x4 o = {f2bf(v.x), f2bf(v.y), f2bf(v.z), f2bf(v.w)};
  *reinterpret_cast<u16x4*>(dst + i) = o;
}

// batched activation convert: 6 tensors of 8388608 f32, grid (8192, 6)
__global__ __launch_bounds__(256) void cvt6_kernel(
    const float* __restrict__ s0, const float* __restrict__ s1,
    const float* __restrict__ s2, const float* __restrict__ s3,
    const float* __restrict__ s4, const float* __restrict__ s5,
    unsigned short* __restrict__ d0, unsigned short* __restrict__ d1,
    unsigned short* __restrict__ d2, unsigned short* __restrict__ d3,
    unsigned short* __restrict__ d4, unsigned short* __restrict__ d5) {
  int which = blockIdx.y;
  const float* src = (which == 0) ? s0 : (which == 1) ? s1 : (which == 2) ? s2
                     : (which == 3) ? s3 : (which == 4) ? s4 : s5;
  unsigned short* dst = (which == 0) ? d0 : (which == 1) ? d1 : (which == 2) ? d2
                        : (which == 3) ? d3 : (which == 4) ? d4 : d5;
  int i = (blockIdx.x * 256 + threadIdx.x) * 4;
  float4 v = *reinterpret_cast<const float4*>(src + i);
  u16x4 o = {f2bf(v.x), f2bf(v.y), f2bf(v.z), f2bf(v.w)};
  *reinterpret_cast<u16x4*>(dst + i) = o;
}

// ---------------------------------------------------------------- QKV proj
// (round-4 structure: 128x128 tile, combined [128][re32|im32] XOR-swizzled
// tiles, per-batch m-tiles, XCD swizzle 1536 = 8 x 192)
__global__ __launch_bounds__(256, 2) void proj_gemm(
    const unsigned short* __restrict__ qreb, const unsigned short* __restrict__ qimb,
    const unsigned short* __restrict__ kreb, const unsigned short* __restrict__ kimb,
    const unsigned short* __restrict__ vreb, const unsigned short* __restrict__ vimb,
    const unsigned short* __restrict__ wr, const unsigned short* __restrict__ wi,
    const float* __restrict__ br, const float* __restrict__ bi,
    unsigned short* __restrict__ q2, unsigned short* __restrict__ k2,
    unsigned short* __restrict__ vt) {
  __shared__ __align__(16) unsigned short smem[18432];  // 36864 B
  unsigned short (*sA)[64] = (unsigned short (*)[64])(smem);          // [128][64]
  unsigned short (*sW)[64] = (unsigned short (*)[64])(smem + 8192);   // [128][64]
  unsigned short (*sC)[140]  = (unsigned short (*)[140])(smem);       // epilogue m-major
  unsigned short (*sCt)[144] = (unsigned short (*)[144])(smem);       // epilogue n-major

  const int tid = threadIdx.x;
  const int lane = tid & 63;
  const int w = tid >> 6;
  const int lr = lane & 15, lk = lane >> 4;
  const int wm = (w & 1) * 64, wn = (w >> 1) * 64;

  // XCD-aware bijective work swizzle: 1536 blocks = 8 XCD x 192
  const int lin = blockIdx.x + blockIdx.y * 24;
  const int wg = (lin & 7) * 192 + (lin >> 3);
  const int n0 = (wg % 24) * 128;
  const int mt = wg / 24;
  const int sec = n0 >> 10;
  const int bb = mt & 7;
  const int ss0 = (mt >> 3) * 128;
  const int h_base = (n0 & 1023) >> 6;

  const unsigned short* aRe = (sec == 0) ? qreb : ((sec == 1) ? kreb : vreb);
  const unsigned short* aIm = (sec == 0) ? qimb : ((sec == 1) ? kimb : vimb);

  int srow[4], sgsw[4];
  for (int c = 0; c < 4; ++c) {
    int gid = c * 256 + tid;
    srow[c] = gid >> 3;
    sgsw[c] = (gid & 7) ^ (srow[c] & 7);
  }

  f32x4 accre[4][4], accim[4][4];
  for (int i = 0; i < 4; ++i)
    for (int j = 0; j < 4; ++j) {
      accre[i][j] = {0.f, 0.f, 0.f, 0.f};
      accim[i][j] = {0.f, 0.f, 0.f, 0.f};
    }
  const u16x8 sign8 = {0x8000, 0x8000, 0x8000, 0x8000, 0x8000, 0x8000, 0x8000, 0x8000};

  for (int k0 = 0; k0 < 1024; k0 += 32) {
    for (int c = 0; c < 4; ++c) {
      int row = srow[c], gsw = sgsw[c];
      int kcol = k0 + (gsw & 3) * 8;
      size_t aoff = (size_t)((ss0 + row) * 8 + bb) * 1024 + kcol;
      gload_lds16((gsw < 4 ? aRe : aIm) + aoff, smem + (c * 256 + w * 64) * 8);
      size_t woff = (size_t)(n0 + row) * 1024 + kcol;
      gload_lds16((gsw < 4 ? wr : wi) + woff, smem + 8192 + (c * 256 + w * 64) * 8);
    }
    __syncthreads();

    u16x8 fWr[4], fWi[4];
    for (int ni = 0; ni < 4; ++ni) {
      int R = wn + ni * 16 + lr, sw = R & 7;
      fWr[ni] = *(const u16x8*)&sW[R][(lk ^ sw) * 8];
      fWi[ni] = *(const u16x8*)&sW[R][((4 + lk) ^ sw) * 8];
    }
    for (int mi = 0; mi < 4; ++mi) {
      int R = wm + mi * 16 + lr, sw = R & 7;
      u16x8 ar = *(const u16x8*)&sA[R][(lk ^ sw) * 8];
      u16x8 ai = *(const u16x8*)&sA[R][((4 + lk) ^ sw) * 8];
      u16x8 nai = ai ^ sign8;
      for (int ni = 0; ni < 4; ++ni) {
        accre[mi][ni] = mfma_bf16(ar, fWr[ni], accre[mi][ni]);
        accre[mi][ni] = mfma_bf16(nai, fWi[ni], accre[mi][ni]);
        accim[mi][ni] = mfma_bf16(ar, fWi[ni], accim[mi][ni]);
        accim[mi][ni] = mfma_bf16(ai, fWr[ni], accim[mi][ni]);
      }
    }
    __syncthreads();
  }

  float vbr[4], vbi[4];
  for (int ni = 0; ni < 4; ++ni) {
    int nabs = n0 + wn + ni * 16 + lr;
    vbr[ni] = br[nabs];
    vbi[ni] = bi[nabs];
  }

  if (sec < 2) {
    unsigned short* dst = (sec == 0) ? q2 : k2;
#define QK_PASS(ACC, BV, POFF)                                                  \
    for (int ni = 0; ni < 4; ++ni)                                              \
      for (int mi = 0; mi < 4; ++mi)                                            \
        for (int r = 0; r < 4; ++r)                                             \
          sC[wm + mi * 16 + lk * 4 + r][wn + ni * 16 + lr] =                    \
              f2bf(ACC[mi][ni][r] + BV[ni]);                                    \
    __syncthreads();                                                            \
    for (int it = 0; it < 8; ++it) {                                            \
      int c = it * 256 + tid;                                                   \
      int m = c >> 4, sub = c & 15, h_i = sub >> 3, d8 = sub & 7;               \
      u16x8 v = *(const u16x8*)&sC[m][h_i * 64 + d8 * 8];                       \
      size_t addr = ((size_t)((bb * 16 + h_base + h_i) * 1024 + ss0 + m)) * 128 \
                    + POFF + d8 * 8;                                            \
      *(u16x8*)(dst + addr) = v;                                                \
    }                                                                           \
    __syncthreads();
    QK_PASS(accre, vbr, 0)
    QK_PASS(accim, vbi, 64)
#undef QK_PASS
  } else {
#define VT_PASS(ACC, BV, POFF)                                                  \
    for (int ni = 0; ni < 4; ++ni)                                              \
      for (int mi = 0; mi < 4; ++mi)                                            \
        for (int r = 0; r < 4; ++r)                                             \
          sCt[wn + ni * 16 + lr][wm + mi * 16 + lk * 4 + r] =                   \
              f2bf(ACC[mi][ni][r] + BV[ni]);                                    \
    __syncthreads();                                                            \
    for (int it = 0; it < 8; ++it) {                                            \
      int c = it * 256 + tid;                                                   \
      int nl = c >> 4, sub = c & 15;                                            \
      int h_i = nl >> 6, d = nl & 63;                                           \
      u16x8 v = *(const u16x8*)&sCt[nl][sub * 8];                               \
      size_t addr = ((size_t)(bb * 16 + h_base + h_i) * 128 + d + POFF) * 1024  \
                    + ss0 + sub * 8;                                            \
      *(u16x8*)(vt + addr) = v;                                                 \
    }                                                                           \
    __syncthreads();
    VT_PASS(accre, vbr, 0)
    VT_PASS(accim, vbi, 64)
#undef VT_PASS
  }
}

// ---------------------------------------------------------------- attention
// 1D grid 2048, XCD-locality mapping. 4 waves x 16 q-rows. Q in registers.
// Single-buffer K/V (replay-proven sync: stage -> sync -> compute -> sync).
// LDS tiles XOR-swizzled (16B granule ^= row&7) via pre-swizzled global source.
__global__ __launch_bounds__(256, 2) void attn_kernel(
    const unsigned short* __restrict__ q2, const unsigned short* __restrict__ k2,
    const unsigned short* __restrict__ vt,
    unsigned short* __restrict__ aor, unsigned short* __restrict__ aoi) {
  __shared__ unsigned short sK[64][128];   // 16 KB
  __shared__ unsigned short sV[128][64];   // 16 KB
  __shared__ unsigned short sP[4][16][72]; // ~9 KB, +8 pad

  const int tid = threadIdx.x, lane = tid & 63, w = tid >> 6;
  const int lr = lane & 15, lk = lane >> 4;
  const int lin = blockIdx.x;
  const int idx = lin >> 3;
  const int bh = (lin & 7) * 16 + (idx >> 4);
  const int q0 = (idx & 15) * 64;
  const int bb = bh >> 4, hh = bh & 15;

  const unsigned short* kbase = k2 + (size_t)bh * 131072;
  const unsigned short* vbase = vt + (size_t)bh * 131072;

  // Q fragments in registers (16 VGPRs), read once
  const int qrow = q0 + w * 16 + lr;
  u16x8 qf[4];
#pragma unroll
  for (int ks = 0; ks < 4; ++ks)
    qf[ks] = *(const u16x8*)(q2 + (size_t)bh * 131072 + (size_t)qrow * 128 +
                             ks * 32 + lk * 8);

  f32x4 o[8];
#pragma unroll
  for (int i = 0; i < 8; ++i) o[i] = {0.f, 0.f, 0.f, 0.f};
  float mrun[4] = {-1e30f, -1e30f, -1e30f, -1e30f};
  float lrun[4] = {0.f, 0.f, 0.f, 0.f};
  const float SC = 0.125f;  // 1/sqrt(64)

#pragma unroll 1
  for (int t0 = 0; t0 < 1024; t0 += 64) {
    // stage K tile (64 x 128), swizzled source
    const unsigned short* kb = kbase + (size_t)t0 * 128;
#pragma unroll
    for (int c = 0; c < 4; ++c) {
      int rb = (w * 4 + c) * 4;
      int row = rb + (lane >> 4);
      int blk = (lane & 15) ^ (row & 7);
      gload_lds16(kb + (size_t)row * 128 + blk * 8, &sK[rb][0]);
    }
    // stage V tile (128 x 64), swizzled source
    const unsigned short* vb = vbase + t0;
#pragma unroll
    for (int c = 0; c < 4; ++c) {
      int rb = (w * 4 + c) * 8;
      int row = rb + (lane >> 3);
      int blk = (lane & 7) ^ (row & 7);
      gload_lds16(vb + (size_t)row * 1024 + blk * 8, &sV[rb][0]);
    }
    __syncthreads();

    // scores tile: rows = wave's 16 q-rows, cols = 64 t
    f32x4 sc[4];
#pragma unroll
    for (int nj = 0; nj < 4; ++nj) sc[nj] = {0.f, 0.f, 0.f, 0.f};
    __builtin_amdgcn_s_setprio(1);
#pragma unroll
    for (int ks = 0; ks < 4; ++ks) {
#pragma unroll
      for (int nj = 0; nj < 4; ++nj) {
        int krow = nj * 16 + lr;
        u16x8 kf = *(const u16x8*)&sK[krow][((ks * 4 + lk) ^ (krow & 7)) * 8];
        sc[nj] = mfma_bf16(qf[ks], kf, sc[nj]);
      }
    }
    __builtin_amdgcn_s_setprio(0);

    // online softmax (row r of this lane = 4*lk + r)
#pragma unroll
    for (int r = 0; r < 4; ++r) {
      float s0 = sc[0][r] * SC, s1 = sc[1][r] * SC;
      float s2 = sc[2][r] * SC, s3 = sc[3][r] * SC;
      float mx = fmaxf(fmaxf(s0, s1), fmaxf(s2, s3));
      for (int msk = 1; msk < 16; msk <<= 1) mx = fmaxf(mx, __shfl_xor(mx, msk));
      float mnew = fmaxf(mrun[r], mx);
      float corr = __expf(mrun[r] - mnew);
      float p0 = __expf(s0 - mnew), p1 = __expf(s1 - mnew);
      float p2 = __expf(s2 - mnew), p3 = __expf(s3 - mnew);
      float rs = p0 + p1 + p2 + p3;
      for (int msk = 1; msk < 16; msk <<= 1) rs += __shfl_xor(rs, msk);
      lrun[r] = lrun[r] * corr + rs;
      mrun[r] = mnew;
#pragma unroll
      for (int ni = 0; ni < 8; ++ni) o[ni][r] *= corr;
      int prow = lk * 4 + r;
      sP[w][prow][0 * 16 + lr] = f2bf(p0);
      sP[w][prow][1 * 16 + lr] = f2bf(p1);
      sP[w][prow][2 * 16 + lr] = f2bf(p2);
      sP[w][prow][3 * 16 + lr] = f2bf(p3);
    }

    // PV: O[s, dd] += P[s, t] * VT[dd, t]
    __builtin_amdgcn_s_setprio(1);
#pragma unroll
    for (int ks = 0; ks < 2; ++ks) {
      u16x8 pf = *(const u16x8*)&sP[w][lr][ks * 32 + lk * 8];
#pragma unroll
      for (int ni = 0; ni < 8; ++ni) {
        int vrow = ni * 16 + lr;
        u16x8 vf = *(const u16x8*)&sV[vrow][((ks * 4 + lk) ^ (vrow & 7)) * 8];
        o[ni] = mfma_bf16(pf, vf, o[ni]);
      }
    }
    __builtin_amdgcn_s_setprio(0);
    __syncthreads();
  }

#pragma unroll
  for (int r = 0; r < 4; ++r) {
    float inv = 1.0f / lrun[r];
#pragma unroll
    for (int ni = 0; ni < 8; ++ni) o[ni][r] *= inv;
  }
#pragma unroll
  for (int ni = 0; ni < 8; ++ni) {
    int dd = ni * 16 + lr;
#pragma unroll
    for (int r = 0; r < 4; ++r) {
      int sg = q0 + w * 16 + lk * 4 + r;
      size_t tok = (size_t)sg * 8 + bb;
      if (dd < 64)
        aor[tok * 1024 + hh * 64 + dd] = f2bf(o[ni][r]);
      else
        aoi[tok * 1024 + hh * 64 + (dd - 64)] = f2bf(o[ni][r]);
    }
  }
}

// ---------------------------------------------------------------- out proj
// Combined [128][re32|im32] XOR-swizzled tiles; XCD swizzle (512 = 8 x 64).
__global__ __launch_bounds__(256, 2) void out_gemm(
    const unsigned short* __restrict__ ar, const unsigned short* __restrict__ ai,
    const unsigned short* __restrict__ wr, const unsigned short* __restrict__ wi,
    const float* __restrict__ br, const float* __restrict__ bi,
    float* __restrict__ out) {
  __shared__ __align__(16) unsigned short smem[16384];  // 32 KB
  unsigned short (*sA)[64] = (unsigned short (*)[64])(smem);
  unsigned short (*sW)[64] = (unsigned short (*)[64])(smem + 8192);

  const int tid = threadIdx.x;
  const int lane = tid & 63;
  const int w = tid >> 6;
  const int lr = lane & 15, lk = lane >> 4;
  const int wm = (w & 1) * 64, wn = (w >> 1) * 64;

  const int lin = blockIdx.x;
  const int wg = (lin & 7) * 64 + (lin >> 3);
  const int n0 = (wg & 7) * 128;
  const int m0 = (wg >> 3) * 128;

  int srow[4], sgsw[4];
  for (int c = 0; c < 4; ++c) {
    int gid = c * 256 + tid;
    srow[c] = gid >> 3;
    sgsw[c] = (gid & 7) ^ (srow[c] & 7);
  }

  f32x4 accre[4][4], accim[4][4];
  for (int i = 0; i < 4; ++i)
    for (int j = 0; j < 4; ++j) {
      accre[i][j] = {0.f, 0.f, 0.f, 0.f};
      accim[i][j] = {0.f, 0.f, 0.f, 0.f};
    }
  const u16x8 sign8 = {0x8000, 0x8000, 0x8000, 0x8000, 0x8000, 0x8000, 0x8000, 0x8000};

  for (int k0 = 0; k0 < 1024; k0 += 32) {
    for (int c = 0; c < 4; ++c) {
      int row = srow[c], gsw = sgsw[c];
      int kcol = k0 + (gsw & 3) * 8;
      size_t aoff = (size_t)(m0 + row) * 1024 + kcol;
      gload_lds16((gsw < 4 ? ar : ai) + aoff, smem + (c * 256 + w * 64) * 8);
      size_t woff = (size_t)(n0 + row) * 1024 + kcol;
      gload_lds16((gsw < 4 ? wr : wi) + woff, smem + 8192 + (c * 256 + w * 64) * 8);
    }
    __syncthreads();

    u16x8 fWr[4], fWi[4];
    for (int ni = 0; ni < 4; ++ni) {
      int R = wn + ni * 16 + lr, sw = R & 7;
      fWr[ni] = *(const u16x8*)&sW[R][(lk ^ sw) * 8];
      fWi[ni] = *(const u16x8*)&sW[R][((4 + lk) ^ sw) * 8];
    }
    for (int mi = 0; mi < 4; ++mi) {
      int R = wm + mi * 16 + lr, sw = R & 7;
      u16x8 a_r = *(const u16x8*)&sA[R][(lk ^ sw) * 8];
      u16x8 a_i = *(const u16x8*)&sA[R][((4 + lk) ^ sw) * 8];
      u16x8 na_i = a_i ^ sign8;
      for (int ni = 0; ni < 4; ++ni) {
        accre[mi][ni] = mfma_bf16(a_r, fWr[ni], accre[mi][ni]);
        accre[mi][ni] = mfma_bf16(na_i, fWi[ni], accre[mi][ni]);
        accim[mi][ni] = mfma_bf16(a_r, fWi[ni], accim[mi][ni]);
        accim[mi][ni] = mfma_bf16(a_i, fWr[ni], accim[mi][ni]);
      }
    }
    __syncthreads();
  }

  for (int ni = 0; ni < 4; ++ni) {
    int n = n0 + wn + ni * 16 + lr;
    float vbr = br[n], vbi = bi[n];
    for (int mi = 0; mi < 4; ++mi) {
      for (int r = 0; r < 4; ++r) {
        int m = m0 + wm + mi * 16 + lk * 4 + r;
        out[(size_t)m * 1024 + n] = accre[mi][ni][r] + vbr;
        out[8388608 + (size_t)m * 1024 + n] = accim[mi][ni][r] + vbi;
      }
    }
  }
}

// ---------------------------------------------------------------- launch
extern "C" void kernel_launch(void* const* d_in, const int* in_sizes, int n_in,
                              void* d_out, int out_size, void* d_ws, size_t ws_size,
                              hipStream_t stream) {
  const float* qre = (const float*)d_in[0];
  const float* qim = (const float*)d_in[1];
  const float* kre = (const float*)d_in[2];
  const float* kim = (const float*)d_in[3];
  const float* vre = (const float*)d_in[4];
  const float* vim = (const float*)d_in[5];
  const float* wqkv_re = (const float*)d_in[6];
  const float* wqkv_im = (const float*)d_in[7];
  const float* bqr = (const float*)d_in[8];
  const float* bqi = (const float*)d_in[9];
  const float* wo_re = (const float*)d_in[10];
  const float* wo_im = (const float*)d_in[11];
  const float* bor = (const float*)d_in[12];
  const float* boi = (const float*)d_in[13];

  char* ws = (char*)d_ws;
  unsigned short* wr_bf  = (unsigned short*)(ws + 0);          //  6.29 MB
  unsigned short* wi_bf  = (unsigned short*)(ws + 6291456);
  unsigned short* wor_bf = (unsigned short*)(ws + 12582912);
  unsigned short* woi_bf = (unsigned short*)(ws + 14680064);
  // activation bf16 (dead after proj_gemm)
  unsigned short* qreb   = (unsigned short*)(ws + 16777216);
  unsigned short* qimb   = (unsigned short*)(ws + 33554432);
  unsigned short* kreb   = (unsigned short*)(ws + 50331648);
  unsigned short* kimb   = (unsigned short*)(ws + 67108864);
  unsigned short* vreb   = (unsigned short*)(ws + 83886080);
  unsigned short* vimb   = (unsigned short*)(ws + 100663296);
  unsigned short* q2     = (unsigned short*)(ws + 117440512);  // 33.55 MB
  unsigned short* k2     = (unsigned short*)(ws + 150994944);
  unsigned short* vt     = (unsigned short*)(ws + 184549376);  // end 218.1 MB
  // attn outputs alias the dead activation region
  unsigned short* aor    = (unsigned short*)(ws + 16777216);
  unsigned short* aoi    = (unsigned short*)(ws + 33554432);

  cvt_kernel<<<3072, 256, 0, stream>>>(wqkv_re, wr_bf, 3145728);
  cvt_kernel<<<3072, 256, 0, stream>>>(wqkv_im, wi_bf, 3145728);
  cvt_kernel<<<1024, 256, 0, stream>>>(wo_re, wor_bf, 1048576);
  cvt_kernel<<<1024, 256, 0, stream>>>(wo_im, woi_bf, 1048576);
  cvt6_kernel<<<dim3(8192, 6), 256, 0, stream>>>(qre, qim, kre, kim, vre, vim,
                                                 qreb, qimb, kreb, kimb, vreb, vimb);

  proj_gemm<<<dim3(24, 64), 256, 0, stream>>>(qreb, qimb, kreb, kimb, vreb, vimb,
                                              wr_bf, wi_bf, bqr, bqi, q2, k2, vt);
  attn_kernel<<<2048, 256, 0, stream>>>(q2, k2, vt, aor, aoi);
  out_gemm<<<512, 256, 0, stream>>>(aor, aoi, wor_bf, woi_bf, bor, boi,
                                    (float*)d_out);
}